// Round 6
// baseline (175.049 us; speedup 1.0000x reference)
//
#include <hip/hip_runtime.h>

// Median blur 3x3, replicate borders, NHWC fp32 [B, 512, 512, 3].
// Exact median-of-9: per-row (min3, med3, max3) triples, then
//   med9 = med3( max3(mins), med3(meds), min3(maxes) )
//
// v5: LDS-staged streaming. v1-v4 post-mortem: four structurally different
// kernels (scalar / float4 L,M,R / pinned-MLP / shuffle) all run 60+-3us at
// ~3.3 TB/s combined R+W -- invariant under 4x instruction-count changes,
// so the limiter is the memory system's service rate for the ACCESS PATTERN
// (10x 1KB chunks at 6KB stride per wave, halo lines re-touched by 3 blocks
// at different times), not MLP or instruction count. Fills/copies that
// stream contiguously hit 6.3-6.9 TB/s on this part.
// v5 makes global traffic shape-identical to a copy:
//   - each block stages its 10-row band (60 KB, contiguous) into LDS via
//     __builtin_amdgcn_global_load_lds width=16 (direct-to-LDS, linear
//     sweep, no VGPR round-trip),
//   - median network reads LDS (conflict-free b128 pattern),
//   - writes a contiguous 48 KB output band.
//   - 60 KB LDS -> 2 blocks/CU: one block computes while the other stages.

#define IMG_H 512
#define IMG_W 512
#define IMG_C 3
#define ROW_F (IMG_W * IMG_C)   // 1536 floats per row
#define TILE_H 8                // output rows per block
#define NROWS (TILE_H + 2)      // staged input rows (10)
#define TPB (ROW_F / 4)         // 384 threads = 6 waves, one float4 column each

__device__ __forceinline__ float med3f(float a, float b, float c) {
    return __builtin_amdgcn_fmed3f(a, b, c);
}
__device__ __forceinline__ float min3f(float a, float b, float c) {
    return fminf(fminf(a, b), c);
}
__device__ __forceinline__ float max3f(float a, float b, float c) {
    return fmaxf(fmaxf(a, b), c);
}

__device__ __forceinline__ int clampRow(int r) {
    return (r < 0) ? 0 : (r > IMG_H - 1 ? IMG_H - 1 : r);
}

typedef __attribute__((address_space(1))) const void GASV;
typedef __attribute__((address_space(3))) void LASV;

__global__ __launch_bounds__(TPB) void median3x3_v5(
        const float* __restrict__ in, float* __restrict__ out) {
    __shared__ __align__(16) float lds[NROWS * ROW_F];   // 61,440 B

    const int t    = threadIdx.x;        // 0..383 (float4 column)
    const int wave = t >> 6;             // 0..5
    const int b    = blockIdx.z;
    const int h0   = blockIdx.y * TILE_H;

    const float* gbase = in  + (size_t)b * IMG_H * ROW_F;
    float*       obase = out + (size_t)b * IMG_H * ROW_F + t * 4;

    // ---- Stage: 10 rows, one contiguous 6KB row per round, direct to LDS.
    // Global source is per-lane (gbase + row*6KB + t*16B); LDS dest is the
    // wave-uniform segment base (HW adds lane*16). Linear layout both sides.
    #pragma unroll
    for (int r = 0; r < NROWS; ++r) {
        const int row = clampRow(h0 - 1 + r);
        const float* src = gbase + (size_t)row * ROW_F + t * 4;
        float*       dst = &lds[r * ROW_F + wave * 256];   // 256 floats = 1KB/wave
        __builtin_amdgcn_global_load_lds((GASV*)src, (LASV*)dst, 16, 0, 0);
    }
    asm volatile("s_waitcnt vmcnt(0)" ::: "memory");
    __syncthreads();

    // ---- Compute: identical median network as v2, operands from LDS.
    // Block spans the full row, so only true image edges need replicate.
    const bool le = (t == 0);
    const bool re = (t == TPB - 1);
    const int  dl = le ? 0 : 4;
    const int  dr = re ? 0 : 4;

    float mn[3][4], md[3][4], mx[3][4];

    auto triple = [&](int r, int s) {
        const float* p = &lds[r * ROW_F + t * 4];
        const float4 M = *(const float4*)p;          // ds_read_b128
        const float4 L = *(const float4*)(p - dl);   // rotated, conflict-free
        const float4 R = *(const float4*)(p + dr);
        const float l0 = le ? M.x : L.y;
        const float l1 = le ? M.y : L.z;
        const float l2 = le ? M.z : L.w;
        const float l3 = M.x;            // wc-3 of column 3 is column 0
        const float r0 = M.w;            // wc+3 of column 0 is column 3
        const float r1 = re ? M.y : R.x;
        const float r2 = re ? M.z : R.y;
        const float r3 = re ? M.w : R.z;
        mn[s][0] = min3f(l0, M.x, r0); md[s][0] = med3f(l0, M.x, r0); mx[s][0] = max3f(l0, M.x, r0);
        mn[s][1] = min3f(l1, M.y, r1); md[s][1] = med3f(l1, M.y, r1); mx[s][1] = max3f(l1, M.y, r1);
        mn[s][2] = min3f(l2, M.z, r2); md[s][2] = med3f(l2, M.z, r2); mx[s][2] = max3f(l2, M.z, r2);
        mn[s][3] = min3f(l3, M.w, r3); md[s][3] = med3f(l3, M.w, r3); mx[s][3] = max3f(l3, M.w, r3);
    };

    triple(0, 0);
    triple(1, 1);

    #pragma unroll
    for (int i = 0; i < TILE_H; ++i) {
        const int h  = h0 + i;
        const int s0 = i % 3, s1 = (i + 1) % 3, s2 = (i + 2) % 3;
        triple(i + 2, s2);

        float4 o;
        o.x = med3f(max3f(mn[s0][0], mn[s1][0], mn[s2][0]),
                    med3f(md[s0][0], md[s1][0], md[s2][0]),
                    min3f(mx[s0][0], mx[s1][0], mx[s2][0]));
        o.y = med3f(max3f(mn[s0][1], mn[s1][1], mn[s2][1]),
                    med3f(md[s0][1], md[s1][1], md[s2][1]),
                    min3f(mx[s0][1], mx[s1][1], mx[s2][1]));
        o.z = med3f(max3f(mn[s0][2], mn[s1][2], mn[s2][2]),
                    med3f(md[s0][2], md[s1][2], md[s2][2]),
                    min3f(mx[s0][2], mx[s1][2], mx[s2][2]));
        o.w = med3f(max3f(mn[s0][3], mn[s1][3], mn[s2][3]),
                    med3f(md[s0][3], md[s1][3], md[s2][3]),
                    min3f(mx[s0][3], mx[s1][3], mx[s2][3]));
        *(float4*)(obase + (size_t)h * ROW_F) = o;   // contiguous 48KB band
    }
}

extern "C" void kernel_launch(void* const* d_in, const int* in_sizes, int n_in,
                              void* d_out, int out_size, void* d_ws, size_t ws_size,
                              hipStream_t stream) {
    const float* in = (const float*)d_in[0];
    float* out = (float*)d_out;

    const int B = in_sizes[0] / (IMG_H * ROW_F);   // 32

    dim3 grid(1, IMG_H / TILE_H, B);               // (1, 64, 32) = 2048 blocks
    dim3 block(TPB, 1, 1);
    median3x3_v5<<<grid, block, 0, stream>>>(in, out);
}

// Round 8
// 174.618 us; speedup vs baseline: 1.0025x; 1.0025x over previous
//
#include <hip/hip_runtime.h>

// Median blur 3x3, replicate borders, NHWC fp32 [B, 512, 512, 3].
// Exact median-of-9: per-row (min3, med3, max3) triples, then
//   med9 = med3( max3(mins), med3(meds), min3(maxes) )
//
// v6b = v4 + NONTEMPORAL STORES (single-variable experiment).
// (v6 failed to compile: __builtin_nontemporal_store rejects HIP's
// float4 class type; use a native clang ext_vector float4 instead.)
// v1-v5 post-mortem: five structurally different kernels (scalar / float4
// L,M,R / pinned-MLP / shuffle single-visit / LDS-staged copy-shape) all
// run 60+-3us at ~3.3 TB/s combined R+W, invariant under instruction
// count, MLP, access pattern, LDS staging, occupancy 14-45%. All models
// (issue rate, Little's law, HBM floor) predict <=32us. Remaining lever:
// the write-once output stream allocates in L2/L3, contending with the
// read stream at the same cache levels (working set is L3-resident).
// v6b marks output stores nontemporal (global_store_dwordx4 nt) so the
// output bypasses cache allocation. Everything else is bit-identical v4.

#define IMG_H 512
#define IMG_W 512
#define IMG_C 3
#define ROW_F (IMG_W * IMG_C)   // 1536 floats per row
#define TILE_H 8                // output rows per thread
#define NROWS (TILE_H + 2)      // input rows touched (10)
#define TPB (ROW_F / 4)         // 384 threads = 6 waves, one float4 column each

typedef float vfloat4 __attribute__((ext_vector_type(4)));   // clang-native

__device__ __forceinline__ float med3f(float a, float b, float c) {
    return __builtin_amdgcn_fmed3f(a, b, c);
}
__device__ __forceinline__ float min3f(float a, float b, float c) {
    return fminf(fminf(a, b), c);
}
__device__ __forceinline__ float max3f(float a, float b, float c) {
    return fmaxf(fmaxf(a, b), c);
}

__device__ __forceinline__ int clampRow(int r) {
    return (r < 0) ? 0 : (r > IMG_H - 1 ? IMG_H - 1 : r);
}

__global__ __launch_bounds__(TPB) void median3x3_v6(
        const float* __restrict__ in, float* __restrict__ out) {
    const int t    = threadIdx.x;        // 0..383 (float4 column index)
    const int lane = t & 63;
    const int b    = blockIdx.z;
    const int h0   = blockIdx.y * TILE_H;

    const float* base  = in  + (size_t)b * IMG_H * ROW_F + t * 4;
    float*       obase = out + (size_t)b * IMG_H * ROW_F + t * 4;

    const bool lef = (lane == 0);        // wave-left edge: shfl_up invalid
    const bool rif = (lane == 63);       // wave-right edge: shfl_down invalid
    const bool il  = (t == 0);           // image left edge (replicate)
    const bool ir  = (t == TPB - 1);     // image right edge (replicate)

    // ---- Phase A: issue ALL loads back-to-back (single-visit M stream) ----
    float4 M[NROWS];
    #pragma unroll
    for (int r = 0; r < NROWS; ++r) {
        const int row = clampRow(h0 - 1 + r);
        M[r] = *(const float4*)(base + (size_t)row * ROW_F);
    }

    // Wave-edge neighbor columns: exec-masked loads, 2 lanes per wave.
    float eA[NROWS], eB[NROWS], eC[NROWS];
    if (lef || rif) {
        const int off = (il || ir) ? 0 : (rif ? 4 : -4);   // clamp at image edge
        float4 Ev[NROWS];
        #pragma unroll
        for (int r = 0; r < NROWS; ++r) {
            const int row = clampRow(h0 - 1 + r);
            Ev[r] = *(const float4*)(base + (size_t)row * ROW_F + off);
        }
        #pragma unroll
        for (int r = 0; r < NROWS; ++r) {
            eA[r] = lef ? Ev[r].y : Ev[r].x;
            eB[r] = lef ? Ev[r].z : Ev[r].y;
            eC[r] = lef ? Ev[r].w : Ev[r].z;
            asm volatile("" :: "v"(eA[r]), "v"(eB[r]), "v"(eC[r]));
        }
    }
    // Liveness barrier: keeps the phase-A loads issued before compute.
    #pragma unroll
    for (int r = 0; r < NROWS; ++r)
        asm volatile("" :: "v"(M[r].x), "v"(M[r].y), "v"(M[r].z), "v"(M[r].w));

    // ---- Phase B: shuffles + median network, rolling vertical window ----
    float mn[3][4], md[3][4], mx[3][4];

    auto triple = [&](int r, int s) {
        const float4 Mv = M[r];
        float l0 = __shfl_up(Mv.y, 1, 64);   // col t*4-3 = left thread's .y
        float l1 = __shfl_up(Mv.z, 1, 64);
        float l2 = __shfl_up(Mv.w, 1, 64);
        float r1 = __shfl_down(Mv.x, 1, 64); // col t*4+4 = right thread's .x
        float r2 = __shfl_down(Mv.y, 1, 64);
        float r3 = __shfl_down(Mv.z, 1, 64);
        if (lef) { l0 = eA[r]; l1 = eB[r]; l2 = eC[r]; }
        if (rif) { r1 = eA[r]; r2 = eB[r]; r3 = eC[r]; }
        if (il)  { l0 = Mv.x; l1 = Mv.y; l2 = Mv.z; }   // replicate left
        if (ir)  { r1 = Mv.y; r2 = Mv.z; r3 = Mv.w; }   // replicate right
        const float l3 = Mv.x;               // in-register neighbors
        const float r0 = Mv.w;
        mn[s][0] = min3f(l0, Mv.x, r0); md[s][0] = med3f(l0, Mv.x, r0); mx[s][0] = max3f(l0, Mv.x, r0);
        mn[s][1] = min3f(l1, Mv.y, r1); md[s][1] = med3f(l1, Mv.y, r1); mx[s][1] = max3f(l1, Mv.y, r1);
        mn[s][2] = min3f(l2, Mv.z, r2); md[s][2] = med3f(l2, Mv.z, r2); mx[s][2] = max3f(l2, Mv.z, r2);
        mn[s][3] = min3f(l3, Mv.w, r3); md[s][3] = med3f(l3, Mv.w, r3); mx[s][3] = max3f(l3, Mv.w, r3);
    };

    triple(0, 0);
    triple(1, 1);

    #pragma unroll
    for (int i = 0; i < TILE_H; ++i) {
        const int h  = h0 + i;
        const int s0 = i % 3, s1 = (i + 1) % 3, s2 = (i + 2) % 3;
        triple(i + 2, s2);

        vfloat4 o;
        o.x = med3f(max3f(mn[s0][0], mn[s1][0], mn[s2][0]),
                    med3f(md[s0][0], md[s1][0], md[s2][0]),
                    min3f(mx[s0][0], mx[s1][0], mx[s2][0]));
        o.y = med3f(max3f(mn[s0][1], mn[s1][1], mn[s2][1]),
                    med3f(md[s0][1], md[s1][1], md[s2][1]),
                    min3f(mx[s0][1], mx[s1][1], mx[s2][1]));
        o.z = med3f(max3f(mn[s0][2], mn[s1][2], mn[s2][2]),
                    med3f(md[s0][2], md[s1][2], md[s2][2]),
                    min3f(mx[s0][2], mx[s1][2], mx[s2][2]));
        o.w = med3f(max3f(mn[s0][3], mn[s1][3], mn[s2][3]),
                    med3f(md[s0][3], md[s1][3], md[s2][3]),
                    min3f(mx[s0][3], mx[s1][3], mx[s2][3]));
        // Nontemporal: output is write-once, never re-read -> don't allocate
        // it in L2/L3; keeps the cache hierarchy for the reused input.
        __builtin_nontemporal_store(o, (vfloat4*)(obase + (size_t)h * ROW_F));
    }
}

extern "C" void kernel_launch(void* const* d_in, const int* in_sizes, int n_in,
                              void* d_out, int out_size, void* d_ws, size_t ws_size,
                              hipStream_t stream) {
    const float* in = (const float*)d_in[0];
    float* out = (float*)d_out;

    const int B = in_sizes[0] / (IMG_H * ROW_F);   // 32

    dim3 grid(1, IMG_H / TILE_H, B);               // (1, 64, 32) = 2048 blocks
    dim3 block(TPB, 1, 1);
    median3x3_v6<<<grid, block, 0, stream>>>(in, out);
}